// Round 7
// baseline (162.773 us; speedup 1.0000x reference)
//
#include <hip/hip_runtime.h>
#include <math.h>

#define WIN 11
#define IMG_H 384
#define IMG_W 512
#define OUT_H (IMG_H - WIN + 1)   // 374
#define OUT_W (IMG_W - WIN + 1)   // 502
#define RPW 2                     // output rows per wave
#define WPB 4                     // waves per block
#define ROWS_PER_BLOCK (RPW * WPB)                      // 8
#define BANDS ((OUT_H + ROWS_PER_BLOCK - 1) / ROWS_PER_BLOCK)  // 47
#define NIMG 48
#define NBLOCKS (BANDS * NIMG)    // 2256
#define BPX (NBLOCKS / 8)         // 282 blocks per XCD

typedef float v2 __attribute__((ext_vector_type(2)));

struct GaussW { float g[WIN]; };

// Packed horizontal 11-tap: even taps hit aligned pairs P[q+m], odd taps hit
// shifted pairs O[p] = {P[p].y, P[p+1].x}. 44 v_pk_fma vs 88 scalar.
__device__ __forceinline__ void horiz11_pk(const v2 (&acc)[4], v2 (&out)[4],
                                           int lane, const GaussW& gw)
{
    v2 P[9];
    #pragma unroll
    for (int q = 0; q < 4; ++q) P[q] = acc[q];
    #pragma unroll
    for (int q = 0; q < 4; ++q) {
        P[4 + q].x = __shfl(acc[q].x, lane + 1, 64);
        P[4 + q].y = __shfl(acc[q].y, lane + 1, 64);
    }
    P[8].x = __shfl(acc[0].x, lane + 2, 64);
    P[8].y = __shfl(acc[0].y, lane + 2, 64);
    v2 O[8];
    #pragma unroll
    for (int p = 0; p < 8; ++p) { O[p].x = P[p].y; O[p].y = P[p + 1].x; }
    #pragma unroll
    for (int q = 0; q < 4; ++q) {
        v2 o = 0.f;
        #pragma unroll
        for (int m = 0; m < 6; ++m) {
            v2 gg = gw.g[2 * m];
            o = __builtin_elementwise_fma(gg, P[q + m], o);
        }
        #pragma unroll
        for (int m = 0; m < 5; ++m) {
            v2 gg = gw.g[2 * m + 1];
            o = __builtin_elementwise_fma(gg, O[q + m], o);
        }
        out[q] = o;
    }
}

__device__ __forceinline__ float row_ssim_pk(v2 (&A)[5][4], int lane, int c0,
                                             const GaussW& gw)
{
    v2 h[5][4];
    #pragma unroll
    for (int ch = 0; ch < 5; ++ch) horiz11_pk(A[ch], h[ch], lane, gw);
    const v2 C1 = 1e-4f, C2 = 9e-4f, two = 2.f;
    float s = 0.f;
    #pragma unroll
    for (int q = 0; q < 4; ++q) {
        v2 mu1 = h[0][q], mu2 = h[1][q];
        v2 mu1s = mu1 * mu1, mu2s = mu2 * mu2, m12 = mu1 * mu2;
        v2 s1  = h[2][q] - mu1s;
        v2 s2  = h[3][q] - mu2s;
        v2 s12 = h[4][q] - m12;
        v2 num = __builtin_elementwise_fma(two, m12, C1) *
                 __builtin_elementwise_fma(two, s12, C2);
        v2 den = (mu1s + mu2s + C1) * (s1 + s2 + C2);
        float r0 = num.x * __builtin_amdgcn_rcpf(den.x);
        float r1 = num.y * __builtin_amdgcn_rcpf(den.y);
        int c = c0 + 2 * q;
        s += (c < OUT_W) ? r0 : 0.f;
        s += (c + 1 < OUT_W) ? r1 : 0.f;
    }
    return s;
}

// 256-thread blocks, 4 blocks/CU (128-VGPR cap): room for the 80-float
// accumulator set in arch VGPRs (no AGPR shuttle), 16 waves/CU residency.
__global__ __launch_bounds__(256, 4) void ssim_fused_kernel(
    const float* __restrict__ X, const float* __restrict__ Y,
    double* __restrict__ slots, GaussW gw)
{
    const int tid  = threadIdx.x;
    const int wave = tid >> 6;
    const int lane = tid & 63;

    // XCD-aware swizzle: round-robin id%8 across XCDs -> give each XCD a
    // contiguous (img, band) run so band halos hit its private L2.
    const int id   = blockIdx.x;
    const int wid  = (id & 7) * BPX + (id >> 3);
    const int img  = wid / BANDS;
    const int band = wid % BANDS;
    const int r0   = band * ROWS_PER_BLOCK + wave * RPW;

    const int c0 = lane << 3;
    float sum = 0.f;

    if (r0 < OUT_H) {   // only wave 3 of the last band per image is idle
        const float* __restrict__ Xb = X + ((size_t)img * IMG_H + r0) * IMG_W + c0;
        const float* __restrict__ Yb = Y + ((size_t)img * IMG_H + r0) * IMG_W + c0;

        v2 A[RPW][5][4];
        #pragma unroll
        for (int r = 0; r < RPW; ++r)
            #pragma unroll
            for (int ch = 0; ch < 5; ++ch)
                #pragma unroll
                for (int q = 0; q < 4; ++q) A[r][ch][q] = 0.f;

        #pragma unroll
        for (int k = 0; k < RPW + WIN - 1; ++k) {   // 12 input rows, no clamp
            const float* rx = Xb + (size_t)k * IMG_W;  // max row = 372+11=383
            const float* ry = Yb + (size_t)k * IMG_W;
            float4 xa = *(const float4*)(rx);
            float4 xb = *(const float4*)(rx + 4);
            float4 ya = *(const float4*)(ry);
            float4 yb = *(const float4*)(ry + 4);
            v2 xs[4] = {{xa.x, xa.y}, {xa.z, xa.w}, {xb.x, xb.y}, {xb.z, xb.w}};
            v2 ys[4] = {{ya.x, ya.y}, {ya.z, ya.w}, {yb.x, yb.y}, {yb.z, yb.w}};
            #pragma unroll
            for (int r = 0; r < RPW; ++r) {
                if (k - r >= 0 && k - r < WIN) {     // compile-time after unroll
                    v2 g = gw.g[k - r];
                    #pragma unroll
                    for (int q = 0; q < 4; ++q) {
                        v2 x = xs[q], y = ys[q];
                        A[r][0][q] = __builtin_elementwise_fma(g, x, A[r][0][q]);
                        A[r][1][q] = __builtin_elementwise_fma(g, y, A[r][1][q]);
                        v2 t = g * x;
                        A[r][2][q] = __builtin_elementwise_fma(t, x, A[r][2][q]);
                        A[r][4][q] = __builtin_elementwise_fma(t, y, A[r][4][q]);
                        v2 u = g * y;
                        A[r][3][q] = __builtin_elementwise_fma(u, y, A[r][3][q]);
                    }
                }
            }
        }

        sum = row_ssim_pk(A[0], lane, c0, gw) + row_ssim_pk(A[1], lane, c0, gw);

        #pragma unroll
        for (int off = 32; off; off >>= 1)
            sum += __shfl_down(sum, off, 64);
    }

    __shared__ float ws[WPB];
    if (lane == 0) ws[wave] = sum;      // idle wave stores 0
    __syncthreads();
    if (tid == 0)
        slots[id] = (double)(ws[0] + ws[1] + ws[2] + ws[3]);  // plain store —
                                                              // no memset node
}

__global__ void ssim_finalize_kernel(const double* __restrict__ slots,
                                     float* __restrict__ out, double inv_count)
{
    const int t = threadIdx.x;          // 256 threads
    double s = 0.0;
    for (int i = t; i < NBLOCKS; i += 256) s += slots[i];
    #pragma unroll
    for (int off = 32; off; off >>= 1)
        s += __shfl_down(s, off, 64);
    __shared__ double w[4];
    if ((t & 63) == 0) w[t >> 6] = s;
    __syncthreads();
    if (t == 0) out[0] = (float)(1.0 - (w[0] + w[1] + w[2] + w[3]) * inv_count);
}

extern "C" void kernel_launch(void* const* d_in, const int* in_sizes, int n_in,
                              void* d_out, int out_size, void* d_ws, size_t ws_size,
                              hipStream_t stream) {
    const float* X = (const float*)d_in[0];
    const float* Y = (const float*)d_in[1];
    float* out = (float*)d_out;
    double* slots = (double*)d_ws;      // NBLOCKS doubles = 18 KB

    GaussW gw;
    {
        double g[WIN], ssum = 0.0;
        for (int i = 0; i < WIN; ++i) {
            double d = (double)i - WIN / 2;
            g[i] = exp(-(d * d) / (2.0 * 1.5 * 1.5));
            ssum += g[i];
        }
        for (int i = 0; i < WIN; ++i) gw.g[i] = (float)(g[i] / ssum);
    }

    ssim_fused_kernel<<<NBLOCKS, 256, 0, stream>>>(X, Y, slots, gw);

    const double inv_count = 1.0 / ((double)NIMG * OUT_H * OUT_W);
    ssim_finalize_kernel<<<1, 256, 0, stream>>>(slots, out, inv_count);
}

// Round 8
// 130.891 us; speedup vs baseline: 1.2436x; 1.2436x over previous
//
#include <hip/hip_runtime.h>
#include <math.h>

#define WIN 11
#define IMG_H 384
#define IMG_W 512
#define OUT_H (IMG_H - WIN + 1)   // 374
#define OUT_W (IMG_W - WIN + 1)   // 502
#define RPW 2                     // output rows per wave
#define NPAIRS (OUT_H / RPW)      // 187 (exact: 374 = 2*187)
#define NIMG 48
#define NBLOCKS (NPAIRS * NIMG)   // 8976 one-wave blocks
#define BLOCKS_PER_XCD (NBLOCKS / 8)  // 1122
#define NBUCKETS 256

struct GaussW { float g[WIN]; };

__device__ __forceinline__ void horiz11(const float (&acc)[8], float (&out)[8],
                                        int lane, const GaussW& gw)
{
    float v[18];
    #pragma unroll
    for (int j = 0; j < 8; ++j) v[j] = acc[j];
    #pragma unroll
    for (int j = 0; j < 8; ++j) v[8 + j] = __shfl(acc[j], lane + 1, 64);
    v[16] = __shfl(acc[0], lane + 2, 64);
    v[17] = __shfl(acc[1], lane + 2, 64);
    #pragma unroll
    for (int j = 0; j < 8; ++j) {
        float o = 0.f;
        #pragma unroll
        for (int k = 0; k < WIN; ++k) o = fmaf(gw.g[k], v[j + k], o);
        out[j] = o;
    }
}

__device__ __forceinline__ float row_ssim(float (&acc)[5][8], int lane, int c0,
                                          const GaussW& gw)
{
    float h[5][8];
    #pragma unroll
    for (int ch = 0; ch < 5; ++ch) horiz11(acc[ch], h[ch], lane, gw);
    const float C1 = 1e-4f, C2 = 9e-4f;
    float s = 0.f;
    #pragma unroll
    for (int j = 0; j < 8; ++j) {
        float mu1 = h[0][j], mu2 = h[1][j];
        float mu1s = mu1 * mu1, mu2s = mu2 * mu2, m12 = mu1 * mu2;
        float s1  = h[2][j] - mu1s;
        float s2  = h[3][j] - mu2s;
        float s12 = h[4][j] - m12;
        float num = fmaf(2.f, m12, C1) * fmaf(2.f, s12, C2);
        float den = (mu1s + mu2s + C1) * (s1 + s2 + C2);
        float ssim = num * __builtin_amdgcn_rcpf(den);
        s += (c0 + j < OUT_W) ? ssim : 0.f;
    }
    return s;
}

// 1-wave blocks. min-waves/EU = 3 -> unified VGPR+AGPR cap ~170: enough for
// the full 80-float accumulator set IN ARCH VGPRS (no v_accvgpr shuttle,
// which at (64,4) doubled issue count) plus ~10 loads in flight.
// gfx950 lesson: launch_bounds' 2nd arg caps the UNIFIED register file; if
// live state exceeds it the compiler shuttles via AGPRs, then spills.
__global__ __launch_bounds__(64, 3) void ssim_fused_kernel(
    const float* __restrict__ X, const float* __restrict__ Y,
    double* __restrict__ accum, GaussW gw)
{
    const int lane = threadIdx.x & 63;

    // XCD-aware swizzle: dispatch is round-robin id%8 across XCDs; give each
    // XCD a CONTIGUOUS run of (img, row-pair) work so the 10-row halo overlap
    // between adjacent row-pairs hits that XCD's private 4 MB L2.
    const int id   = blockIdx.x;
    const int wid  = (id & 7) * BLOCKS_PER_XCD + (id >> 3);
    const int img  = wid / NPAIRS;
    const int pair = wid % NPAIRS;
    const int r0   = pair * RPW;          // max input row = 372+11 = 383: no clamp
    const int c0   = lane << 3;           // this lane's 8 columns
    const float* __restrict__ Xb = X + ((size_t)img * IMG_H + r0) * IMG_W + c0;
    const float* __restrict__ Yb = Y + ((size_t)img * IMG_H + r0) * IMG_W + c0;

    // ---- vertical 11-tap, 2 output rows, streaming 12 input rows ----
    float a[RPW][5][8];
    #pragma unroll
    for (int r = 0; r < RPW; ++r)
        #pragma unroll
        for (int ch = 0; ch < 5; ++ch)
            #pragma unroll
            for (int j = 0; j < 8; ++j) a[r][ch][j] = 0.f;

    #pragma unroll
    for (int k = 0; k < RPW + WIN - 1; ++k) {   // 12 input rows
        const float* rx = Xb + (size_t)k * IMG_W;
        const float* ry = Yb + (size_t)k * IMG_W;
        float4 xa = *(const float4*)(rx);
        float4 xb = *(const float4*)(rx + 4);
        float4 ya = *(const float4*)(ry);
        float4 yb = *(const float4*)(ry + 4);
        float xs[8] = {xa.x, xa.y, xa.z, xa.w, xb.x, xb.y, xb.z, xb.w};
        float ys[8] = {ya.x, ya.y, ya.z, ya.w, yb.x, yb.y, yb.z, yb.w};
        #pragma unroll
        for (int r = 0; r < RPW; ++r) {
            if (k - r >= 0 && k - r < WIN) {     // compile-time after unroll
                const float g = gw.g[k - r];
                #pragma unroll
                for (int j = 0; j < 8; ++j) {
                    float x = xs[j], y = ys[j];
                    a[r][0][j] = fmaf(g, x, a[r][0][j]);
                    a[r][1][j] = fmaf(g, y, a[r][1][j]);
                    float t = g * x;
                    a[r][2][j] = fmaf(t, x, a[r][2][j]);
                    a[r][4][j] = fmaf(t, y, a[r][4][j]);
                    float u = g * y;
                    a[r][3][j] = fmaf(u, y, a[r][3][j]);
                }
            }
        }
    }

    // ---- horizontal + epilogue (both rows always in-range: 374 = 2*187) ----
    float sum = row_ssim(a[0], lane, c0, gw) + row_ssim(a[1], lane, c0, gw);

    // ---- wave reduction -> one f64 atomic per wave, bucketed ----
    #pragma unroll
    for (int off = 32; off; off >>= 1)
        sum += __shfl_down(sum, off, 64);
    if (lane == 0)
        atomicAdd(&accum[id & (NBUCKETS - 1)], (double)sum);
}

__global__ void ssim_finalize_kernel(const double* __restrict__ accum,
                                     float* __restrict__ out, double inv_count)
{
    const int lane = threadIdx.x;
    double s = 0.0;
    for (int i = lane; i < NBUCKETS; i += 64) s += accum[i];
    #pragma unroll
    for (int off = 32; off; off >>= 1)
        s += __shfl_down(s, off, 64);
    if (lane == 0) out[0] = (float)(1.0 - s * inv_count);
}

extern "C" void kernel_launch(void* const* d_in, const int* in_sizes, int n_in,
                              void* d_out, int out_size, void* d_ws, size_t ws_size,
                              hipStream_t stream) {
    const float* X = (const float*)d_in[0];
    const float* Y = (const float*)d_in[1];
    float* out = (float*)d_out;
    double* accum = (double*)d_ws;

    GaussW gw;
    {
        double g[WIN], ssum = 0.0;
        for (int i = 0; i < WIN; ++i) {
            double d = (double)i - WIN / 2;
            g[i] = exp(-(d * d) / (2.0 * 1.5 * 1.5));
            ssum += g[i];
        }
        for (int i = 0; i < WIN; ++i) gw.g[i] = (float)(g[i] / ssum);
    }

    // d_ws is re-poisoned 0xAA before every call — zero the buckets.
    hipMemsetAsync(accum, 0, NBUCKETS * sizeof(double), stream);

    ssim_fused_kernel<<<NBLOCKS, 64, 0, stream>>>(X, Y, accum, gw);

    const double inv_count = 1.0 / ((double)NIMG * OUT_H * OUT_W);
    ssim_finalize_kernel<<<1, 64, 0, stream>>>(accum, out, inv_count);
}

// Round 9
// 128.977 us; speedup vs baseline: 1.2620x; 1.0148x over previous
//
#include <hip/hip_runtime.h>
#include <math.h>

#define WIN 11
#define IMG_H 384
#define IMG_W 512
#define OUT_H (IMG_H - WIN + 1)   // 374
#define OUT_W (IMG_W - WIN + 1)   // 502
#define RPW 2                     // output rows per wave
#define NPAIRS (OUT_H / RPW)      // 187 (exact: 374 = 2*187)
#define NIMG 48
#define NBLOCKS (NPAIRS * NIMG)   // 8976 one-wave blocks
#define BLOCKS_PER_XCD (NBLOCKS / 8)  // 1122
#define NBUCKETS 256

struct GaussW { float g[WIN]; };

__device__ __forceinline__ void horiz11(const float (&acc)[8], float (&out)[8],
                                        int lane, const GaussW& gw)
{
    float v[18];
    #pragma unroll
    for (int j = 0; j < 8; ++j) v[j] = acc[j];
    #pragma unroll
    for (int j = 0; j < 8; ++j) v[8 + j] = __shfl(acc[j], lane + 1, 64);
    v[16] = __shfl(acc[0], lane + 2, 64);
    v[17] = __shfl(acc[1], lane + 2, 64);
    #pragma unroll
    for (int j = 0; j < 8; ++j) {
        float o = 0.f;
        #pragma unroll
        for (int k = 0; k < WIN; ++k) o = fmaf(gw.g[k], v[j + k], o);
        out[j] = o;
    }
}

__device__ __forceinline__ float row_ssim(float (&acc)[5][8], int lane, int c0,
                                          const GaussW& gw)
{
    float h[5][8];
    #pragma unroll
    for (int ch = 0; ch < 5; ++ch) horiz11(acc[ch], h[ch], lane, gw);
    const float C1 = 1e-4f, C2 = 9e-4f;
    float s = 0.f;
    #pragma unroll
    for (int j = 0; j < 8; ++j) {
        float mu1 = h[0][j], mu2 = h[1][j];
        float mu1s = mu1 * mu1, mu2s = mu2 * mu2, m12 = mu1 * mu2;
        float s1  = h[2][j] - mu1s;
        float s2  = h[3][j] - mu2s;
        float s12 = h[4][j] - m12;
        float num = fmaf(2.f, m12, C1) * fmaf(2.f, s12, C2);
        float den = (mu1s + mu2s + C1) * (s1 + s2 + C2);
        float ssim = num * __builtin_amdgcn_rcpf(den);
        s += (c0 + j < OUT_W) ? ssim : 0.f;
    }
    return s;
}

// 1-wave blocks. KEY CHANGE vs r8: amdgpu_waves_per_eu(3,4) — the explicit
// MAX (=4) stops the allocator from occupancy-chasing down to 64 arch VGPRs
// and shuttling the 80-float accumulator set through AGPRs (r6/r8: VGPR=64,
// VALU-busy 35 µs vs ~18 µs instr floor). min=3 keeps the budget ~170 regs.
// __launch_bounds__' 2nd arg only sets the min — it never stopped the
// squeeze; r5 (no bounds) showed the same math compiles to 136 VGPRs with
// ~27 µs VALU-busy.
__global__
__attribute__((amdgpu_flat_work_group_size(64, 64), amdgpu_waves_per_eu(3, 4)))
void ssim_fused_kernel(
    const float* __restrict__ X, const float* __restrict__ Y,
    double* __restrict__ accum, GaussW gw)
{
    const int lane = threadIdx.x & 63;

    // XCD-aware swizzle: dispatch is round-robin id%8 across XCDs; give each
    // XCD a CONTIGUOUS run of (img, row-pair) work so the 10-row halo overlap
    // between adjacent row-pairs hits that XCD's private 4 MB L2.
    const int id   = blockIdx.x;
    const int wid  = (id & 7) * BLOCKS_PER_XCD + (id >> 3);
    const int img  = wid / NPAIRS;
    const int pair = wid % NPAIRS;
    const int r0   = pair * RPW;          // max input row = 372+11 = 383: no clamp
    const int c0   = lane << 3;           // this lane's 8 columns
    const float* __restrict__ Xb = X + ((size_t)img * IMG_H + r0) * IMG_W + c0;
    const float* __restrict__ Yb = Y + ((size_t)img * IMG_H + r0) * IMG_W + c0;

    // ---- vertical 11-tap, 2 output rows, streaming 12 input rows ----
    float a[RPW][5][8];
    #pragma unroll
    for (int r = 0; r < RPW; ++r)
        #pragma unroll
        for (int ch = 0; ch < 5; ++ch)
            #pragma unroll
            for (int j = 0; j < 8; ++j) a[r][ch][j] = 0.f;

    #pragma unroll
    for (int k = 0; k < RPW + WIN - 1; ++k) {   // 12 input rows
        const float* rx = Xb + (size_t)k * IMG_W;
        const float* ry = Yb + (size_t)k * IMG_W;
        float4 xa = *(const float4*)(rx);
        float4 xb = *(const float4*)(rx + 4);
        float4 ya = *(const float4*)(ry);
        float4 yb = *(const float4*)(ry + 4);
        float xs[8] = {xa.x, xa.y, xa.z, xa.w, xb.x, xb.y, xb.z, xb.w};
        float ys[8] = {ya.x, ya.y, ya.z, ya.w, yb.x, yb.y, yb.z, yb.w};
        #pragma unroll
        for (int r = 0; r < RPW; ++r) {
            if (k - r >= 0 && k - r < WIN) {     // compile-time after unroll
                const float g = gw.g[k - r];
                #pragma unroll
                for (int j = 0; j < 8; ++j) {
                    float x = xs[j], y = ys[j];
                    a[r][0][j] = fmaf(g, x, a[r][0][j]);
                    a[r][1][j] = fmaf(g, y, a[r][1][j]);
                    float t = g * x;
                    a[r][2][j] = fmaf(t, x, a[r][2][j]);
                    a[r][4][j] = fmaf(t, y, a[r][4][j]);
                    float u = g * y;
                    a[r][3][j] = fmaf(u, y, a[r][3][j]);
                }
            }
        }
    }

    // ---- horizontal + epilogue (both rows always in-range: 374 = 2*187) ----
    float sum = row_ssim(a[0], lane, c0, gw) + row_ssim(a[1], lane, c0, gw);

    // ---- wave reduction -> one f64 atomic per wave, bucketed ----
    #pragma unroll
    for (int off = 32; off; off >>= 1)
        sum += __shfl_down(sum, off, 64);
    if (lane == 0)
        atomicAdd(&accum[id & (NBUCKETS - 1)], (double)sum);
}

__global__ void ssim_finalize_kernel(const double* __restrict__ accum,
                                     float* __restrict__ out, double inv_count)
{
    const int lane = threadIdx.x;
    double s = 0.0;
    for (int i = lane; i < NBUCKETS; i += 64) s += accum[i];
    #pragma unroll
    for (int off = 32; off; off >>= 1)
        s += __shfl_down(s, off, 64);
    if (lane == 0) out[0] = (float)(1.0 - s * inv_count);
}

extern "C" void kernel_launch(void* const* d_in, const int* in_sizes, int n_in,
                              void* d_out, int out_size, void* d_ws, size_t ws_size,
                              hipStream_t stream) {
    const float* X = (const float*)d_in[0];
    const float* Y = (const float*)d_in[1];
    float* out = (float*)d_out;
    double* accum = (double*)d_ws;

    GaussW gw;
    {
        double g[WIN], ssum = 0.0;
        for (int i = 0; i < WIN; ++i) {
            double d = (double)i - WIN / 2;
            g[i] = exp(-(d * d) / (2.0 * 1.5 * 1.5));
            ssum += g[i];
        }
        for (int i = 0; i < WIN; ++i) gw.g[i] = (float)(g[i] / ssum);
    }

    // d_ws is re-poisoned 0xAA before every call — zero the buckets.
    hipMemsetAsync(accum, 0, NBUCKETS * sizeof(double), stream);

    ssim_fused_kernel<<<NBLOCKS, 64, 0, stream>>>(X, Y, accum, gw);

    const double inv_count = 1.0 / ((double)NIMG * OUT_H * OUT_W);
    ssim_finalize_kernel<<<1, 64, 0, stream>>>(accum, out, inv_count);
}